// Round 3
// baseline (87.987 us; speedup 1.0000x reference)
//
#include <hip/hip_runtime.h>
#include <math.h>

// x [B=32, C=64, T=32, H=28, W=28] f32, layout idx = ((bc*T + t)*HW + hw).
// LIF recurrence over t (stride HW). Spikes (0/1 f32) out, same layout.
typedef float f4 __attribute__((ext_vector_type(4)));

#define TT   32
#define HW4  196                    // 784/4 float4 per (bc,t) slice
#define BCH  1024                   // half of B*C = 2048; each thread owns 2 images
#define NTH  (BCH * HW4)            // 200704 threads = 3136 waves (12.25/CU)
#define BSTRIDE ((size_t)BCH * TT * HW4)  // float4 offset between the two streams

__device__ __forceinline__ f4 spike4(f4 u) {
    f4 s;
    s.x = u.x > 0.5f ? 1.0f : 0.0f;
    s.y = u.y > 0.5f ? 1.0f : 0.0f;
    s.z = u.z > 0.5f ? 1.0f : 0.0f;
    s.w = u.w > 0.5f ? 1.0f : 0.0f;
    return s;
}

// mem = mem_old*d*(1-s_old) + x_t. s_old ∈ {0,1} exactly, so the select form
// is bit-identical to the reference. __fmul_rn/__fadd_rn forbid FMA
// contraction so rounding matches XLA/numpy's separate mul-then-add.
__device__ __forceinline__ f4 upd4(f4 mem, f4 s, f4 xt, float d) {
    f4 r;
    r.x = __fadd_rn(s.x != 0.0f ? 0.0f : __fmul_rn(mem.x, d), xt.x);
    r.y = __fadd_rn(s.y != 0.0f ? 0.0f : __fmul_rn(mem.y, d), xt.y);
    r.z = __fadd_rn(s.z != 0.0f ? 0.0f : __fmul_rn(mem.z, d), xt.z);
    r.w = __fadd_rn(s.w != 0.0f ? 0.0f : __fmul_rn(mem.w, d), xt.w);
    return r;
}

__global__ __launch_bounds__(64) void lif_fwd_kernel(
        const f4* __restrict__ x,
        const float* __restrict__ decay,
        f4* __restrict__ out) {
    const int tid = blockIdx.x * 64 + threadIdx.x;   // grid exact, no bound check
    const int bc  = tid / HW4;                       // [0, 1024)
    const int hw4 = tid - bc * HW4;
    const size_t baseA = (size_t)bc * (TT * HW4) + (size_t)hw4;
    const size_t baseB = baseA + BSTRIDE;            // image bc + 1024

    // d = sigmoid(decay[0]), step-by-step f32 to match reference rounding.
    const float e = expf(-decay[0]);
    const float d = 1.0f / (1.0f + e);

    // t = 0: mem = x0, spike = (mem > 0.5). NT: read-once / write-once streams.
    f4 memA = __builtin_nontemporal_load(x + baseA);
    f4 memB = __builtin_nontemporal_load(x + baseB);
    f4 sA = spike4(memA);
    f4 sB = spike4(memB);
    __builtin_nontemporal_store(sA, out + baseA);
    __builtin_nontemporal_store(sB, out + baseB);

    // Software pipeline: load t+1 (2 independent streams) before the serial
    // update of step t, so >=2 KB/wave stays outstanding during compute.
    f4 cA = __builtin_nontemporal_load(x + baseA + HW4);
    f4 cB = __builtin_nontemporal_load(x + baseB + HW4);

    #pragma unroll
    for (int t = 1; t < TT; ++t) {
        const bool hasNext = (t + 1 < TT);
        f4 nA{}, nB{};
        if (hasNext) {
            nA = __builtin_nontemporal_load(x + baseA + (size_t)(t + 1) * HW4);
            nB = __builtin_nontemporal_load(x + baseB + (size_t)(t + 1) * HW4);
        }
        memA = upd4(memA, sA, cA, d);
        sA   = spike4(memA);
        __builtin_nontemporal_store(sA, out + baseA + (size_t)t * HW4);
        memB = upd4(memB, sB, cB, d);
        sB   = spike4(memB);
        __builtin_nontemporal_store(sB, out + baseB + (size_t)t * HW4);
        if (hasNext) { cA = nA; cB = nB; }
    }
}

extern "C" void kernel_launch(void* const* d_in, const int* in_sizes, int n_in,
                              void* d_out, int out_size, void* d_ws, size_t ws_size,
                              hipStream_t stream) {
    const f4*    x     = (const f4*)d_in[0];
    const float* decay = (const float*)d_in[1];
    f4*          out   = (f4*)d_out;

    const int block = 64;
    const int grid  = NTH / block;   // 3136, exact
    lif_fwd_kernel<<<grid, block, 0, stream>>>(x, decay, out);
}

// Round 5
// 67.945 us; speedup vs baseline: 1.2950x; 1.2950x over previous
//
#include <hip/hip_runtime.h>
#include <math.h>

// x [B=32, C=64, T=32, H=28, W=28] f32, layout idx = ((bc*T + t)*HW + hw).
// LIF recurrence over t (stride HW). Spikes (0/1 f32) out, same layout.
//
// R4 = R3 retry: x (205.5 MB) fits in the 256 MiB Infinity Cache across graph
// replays IF the output stream doesn't evict it. So: TEMPORAL loads for x
// (allocate in L2/L3), NONTEMPORAL stores for out (write-once, never re-read).
// Uses clang ext_vector_type, since __builtin_nontemporal_store rejects HIP's
// float4 wrapper class.
typedef float f4 __attribute__((ext_vector_type(4)));

#define TT   32
#define HW4  196            // 784/4 float4 per (bc,t) slice
#define BC   (32 * 64)
#define NTHREADS (BC * HW4) // 401408 = 6272 * 64

__device__ __forceinline__ float spike_of(float u) {
    return u > 0.5f ? 1.0f : 0.0f;
}

__global__ __launch_bounds__(64) void lif_fwd_kernel(
        const f4* __restrict__ x,
        const float* __restrict__ decay,
        f4* __restrict__ out) {
    const int tid = blockIdx.x * 64 + threadIdx.x;   // grid exact
    const int bc  = tid / HW4;
    const int hw4 = tid - bc * HW4;
    const size_t base = (size_t)bc * (TT * HW4) + (size_t)hw4;

    // d = sigmoid(decay[0]); step-by-step f32 to match reference rounding.
    const float e = expf(-decay[0]);
    const float d = 1.0f / (1.0f + e);

    // t = 0: mem = x0, spike = (mem > 0.5)
    f4 mem = x[base];            // temporal load: let x allocate in L2/L3
    f4 s;
    s.x = spike_of(mem.x);
    s.y = spike_of(mem.y);
    s.z = spike_of(mem.z);
    s.w = spike_of(mem.w);
    __builtin_nontemporal_store(s, out + base);

    // t >= 1: mem = mem_old*d*(1-s_old) + x_t ; s = (mem > 0.5)
    // s_old ∈ {0,1} exactly, so the select form is bit-identical to the
    // reference's (mem*d)*(1-s). __fmul_rn/__fadd_rn forbid FMA contraction
    // so rounding matches a plain f32 mul-then-add chain.
    #pragma unroll
    for (int t = 1; t < TT; ++t) {
        const f4 xt = x[base + (size_t)t * HW4];
        mem.x = __fadd_rn(s.x != 0.0f ? 0.0f : __fmul_rn(mem.x, d), xt.x);
        mem.y = __fadd_rn(s.y != 0.0f ? 0.0f : __fmul_rn(mem.y, d), xt.y);
        mem.z = __fadd_rn(s.z != 0.0f ? 0.0f : __fmul_rn(mem.z, d), xt.z);
        mem.w = __fadd_rn(s.w != 0.0f ? 0.0f : __fmul_rn(mem.w, d), xt.w);
        s.x = spike_of(mem.x);
        s.y = spike_of(mem.y);
        s.z = spike_of(mem.z);
        s.w = spike_of(mem.w);
        __builtin_nontemporal_store(s, out + base + (size_t)t * HW4);
    }
}

extern "C" void kernel_launch(void* const* d_in, const int* in_sizes, int n_in,
                              void* d_out, int out_size, void* d_ws, size_t ws_size,
                              hipStream_t stream) {
    const f4*    x     = (const f4*)d_in[0];
    const float* decay = (const float*)d_in[1];
    f4*          out   = (f4*)d_out;

    const int block = 64;
    const int grid  = NTHREADS / block;  // 6272, exact
    lif_fwd_kernel<<<grid, block, 0, stream>>>(x, decay, out);
}